// Round 14
// baseline (247.286 us; speedup 1.0000x reference)
//
#include <hip/hip_runtime.h>
#include <hip/hip_bf16.h>

#define HID 128
#define LDK 136    // LDS row stride in shorts (272B) for prep/update kernels
#define CPB 4      // cells per edge-block (1 per wave)
#define CAP 16     // edges per cell (E/G)

// wt regions (bf16 elements), all [128][128] transposed Wt[n][k]
#define WT_M1L 0       // mw1 rows 0..127 (prep_gemm)
#define WT_T   16384   // T fold: Tt[n][a] = sum_f ew2[a][f]*mw1[128+f][n]
#define WT_W2U 32768   // W2U fold: [n][a] = sum_f mw2[a][f]*uw1[f][n]
#define WT_U2  49152
#define WT_TOTAL 65536

typedef __attribute__((ext_vector_type(8))) short bf16x8;
typedef __attribute__((ext_vector_type(4))) float f32x4;

#define MFMA(a, b, c) __builtin_amdgcn_mfma_f32_16x16x32_bf16(a, b, c, 0, 0, 0)

__device__ __forceinline__ float silu_f(float x) {
    return x * (1.0f / (1.0f + __expf(-x)));
}

__device__ __forceinline__ short f2b(float x) {
    __hip_bfloat16 h = __float2bfloat16(x);   // RNE
    return *(short*)&h;
}

__device__ __forceinline__ float b2f(unsigned short u) {
    union { unsigned u32; float f; } v;
    v.u32 = ((unsigned)u) << 16;
    return v.f;
}

// K=128 GEMM, 4 act-row-tiles (rows e4*16+q) x 32 weight cols, act-as-A.
// (used by prep_gemm / update_kernel)
template<int LDB>
__device__ __forceinline__ void gemm128(f32x4 acc[4][2], const short* actb,
                                        const short* __restrict__ w0)
{
    const short* __restrict__ w1 = w0 + 16 * LDB;
    #pragma unroll
    for (int ks = 0; ks < 4; ++ks) {
        bf16x8 wa = *(const bf16x8*)(w0 + ks * 32);
        bf16x8 wb = *(const bf16x8*)(w1 + ks * 32);
        #pragma unroll
        for (int e4 = 0; e4 < 4; ++e4) {
            bf16x8 a = *(const bf16x8*)(actb + e4 * (16 * LDK) + ks * 32);
            acc[e4][0] = MFMA(a, wa, acc[e4][0]);
            acc[e4][1] = MFMA(a, wb, acc[e4][1]);
        }
    }
}

// ---------------------------------------------------------------------------
// prep0: binning | wt cvt (M1L,U2) | T fold | W2U fold | biases | preC
// ---------------------------------------------------------------------------
extern "C" __global__ void __launch_bounds__(256)
prep0(const int* __restrict__ ei, int* __restrict__ cnt, int* __restrict__ bin, int E,
      const float* __restrict__ ew1, const float* __restrict__ eb1,
      const float* __restrict__ ew2, const float* __restrict__ eb2,
      const float* __restrict__ mw1, const float* __restrict__ mw2,
      const float* __restrict__ mb2,
      const float* __restrict__ uw1, const float* __restrict__ ub1,
      const float* __restrict__ uw2,
      const float* __restrict__ gpos,
      short* __restrict__ wt, float* __restrict__ bias2, float* __restrict__ bU,
      float* __restrict__ preC, int G)
{
    int nbin = (E + 255) / 256;
    int b = blockIdx.x;
    int t = threadIdx.x;
    if (b < nbin) {                      // binning: store SOURCE NODE id
        int e = b * 256 + t;
        if (e < E) {
            int j = ei[E + e];
            int i = ei[e];
            int slot = atomicAdd(&cnt[j], 1);
            if (slot < CAP) bin[(size_t)j * CAP + slot] = i;
        }
        return;
    }
    b -= nbin;
    if (b < 128) {                       // transpose-convert M1L | U2
        int idx = b * 256 + t;
        if (idx < 16384) {
            int n = idx >> 7, k = idx & 127;
            wt[WT_M1L + idx] = f2b(mw1[k * HID + n]);
        } else {
            int r = idx - 16384;
            int n = r >> 7, k = r & 127;
            wt[WT_U2 + r] = f2b(uw2[k * HID + n]);
        }
        return;
    }
    b -= 128;
    if (b < 64) {                        // T fold
        int idx = b * 256 + t;
        int n = idx >> 7, a = idx & 127;
        const float* er = ew2 + (size_t)a * HID;
        float s = 0.0f;
        for (int f = 0; f < HID; ++f)
            s = fmaf(er[f], mw1[(size_t)(HID + f) * HID + n], s);
        wt[WT_T + idx] = f2b(s);
        return;
    }
    b -= 64;
    if (b < 64) {                        // W2U fold
        int idx = b * 256 + t;
        int n = idx >> 7, a = idx & 127;
        const float* mr = mw2 + (size_t)a * HID;
        float s = 0.0f;
        for (int f = 0; f < HID; ++f)
            s = fmaf(mr[f], uw1[(size_t)f * HID + n], s);
        wt[WT_W2U + idx] = f2b(s);
        return;
    }
    b -= 64;
    if (b < 1) {                         // bias2 (t<128) and bU (t>=128)
        if (t < HID) {
            float s = 0.0f;
            for (int f = 0; f < HID; ++f)
                s = fmaf(eb2[f], mw1[(size_t)(HID + f) * HID + t], s);
            bias2[t] = s;
        } else if (t < 2 * HID) {
            int n = t - HID;
            float s = 0.0f;
            for (int f = 0; f < HID; ++f)
                s = fmaf(mb2[f], uw1[(size_t)f * HID + n], s);
            bU[n] = s + ub1[n];
        }
        return;
    }
    b -= 1;
    {                                    // preC[cell][f] = gp.ew1[3:6] + eb1 (fp32)
        int idx = b * 256 + t;
        if (idx < G * 16) {
            int cell = idx >> 4, f0 = (idx & 15) * 8;
            const float* gp = gpos + (size_t)cell * 3;
            float g0 = gp[0], g1 = gp[1], g2 = gp[2];
            const float* w3 = ew1 + 3 * HID + f0;
            const float* w4 = ew1 + 4 * HID + f0;
            const float* w5 = ew1 + 5 * HID + f0;
            const float* bb = eb1 + f0;
            float o[8];
            #pragma unroll
            for (int j = 0; j < 8; ++j)
                o[j] = g0 * w3[j] + g1 * w4[j] + g2 * w5[j] + bb[j];
            float* dst = preC + (size_t)cell * HID + f0;
            *(float4*)dst       = make_float4(o[0], o[1], o[2], o[3]);
            *(float4*)(dst + 4) = make_float4(o[4], o[5], o[6], o[7]);
        }
    }
}

// ---------------------------------------------------------------------------
// prep_gemm: pre[node] = emb[node] @ mw1[:128] + mb1 + bias2   (bf16)
// ---------------------------------------------------------------------------
extern "C" __global__ void __launch_bounds__(256, 4)
prep_gemm(const float* __restrict__ emb, const float* __restrict__ mb1,
          const float* __restrict__ bias2, const short* __restrict__ wt,
          unsigned short* __restrict__ pre)
{
    __shared__ short s_x[64 * LDK];
    const int t  = threadIdx.x;
    const int r0 = blockIdx.x * 64;

    {   // stage 64 fp32 rows -> bf16 LDS (padded rows)
        int row = t >> 2, part = t & 3;
        const float4* src = (const float4*)(emb + (size_t)(r0 + row) * HID + part * 32);
        short* dst = s_x + row * LDK + part * 32;
        #pragma unroll
        for (int c = 0; c < 4; ++c) {
            float4 v0 = src[c * 2], v1 = src[c * 2 + 1];
            short4 a4, b4;
            a4.x = f2b(v0.x); a4.y = f2b(v0.y); a4.z = f2b(v0.z); a4.w = f2b(v0.w);
            b4.x = f2b(v1.x); b4.y = f2b(v1.y); b4.z = f2b(v1.z); b4.w = f2b(v1.w);
            *(short4*)(dst + c * 8)     = a4;
            *(short4*)(dst + c * 8 + 4) = b4;
        }
    }
    __syncthreads();

    const int lane = t & 63, q = lane & 15, h = lane >> 4, nb = (t >> 6) * 32;
    f32x4 acc[4][2];
    #pragma unroll
    for (int m = 0; m < 4; ++m) { acc[m][0] = (f32x4)(0.0f); acc[m][1] = (f32x4)(0.0f); }
    gemm128<128>(acc, s_x + q * LDK + h * 8, wt + WT_M1L + (nb + q) * 128 + h * 8);

    #pragma unroll
    for (int nf = 0; nf < 2; ++nf) {
        int n = nb + nf * 16 + q;
        float bb = mb1[n] + bias2[n];
        #pragma unroll
        for (int m = 0; m < 4; ++m)
            #pragma unroll
            for (int r = 0; r < 4; ++r)
                pre[(size_t)(r0 + m * 16 + h * 4 + r) * HID + n] =
                    f2b(acc[m][nf][r] + bb);
    }
}

// ---------------------------------------------------------------------------
// edge kernel: WAVE-PER-CELL, fragment-direct h1 (no h1 LDS, no mid barriers).
// Lane (q,h): h1 for edge q in A-frag layout -> 32 MFMAs acc[8] ->
// silu+pre epi -> cell-sum (4 adds + 2 shfl) -> s_red -> coalesced store.
// ---------------------------------------------------------------------------
extern "C" __global__ void __launch_bounds__(256, 4)
edge_kernel(const float* __restrict__ npos,
            const float* __restrict__ ew1,
            const short* __restrict__ wt,
            const int* __restrict__ bin,
            const unsigned short* __restrict__ pre,
            const float* __restrict__ preC,
            unsigned short* __restrict__ gsum)
{
    __shared__ short s_red[CPB * HID];   // 4 cells x 128 cols (bf16)

    const int t  = threadIdx.x;
    const int c0 = blockIdx.x * CPB;
    const int lane = t & 63, q = lane & 15, h = lane >> 4;
    const int w = t >> 6;                // wave id = cell within block
    const int cell = c0 + w;

    // ---- my A-row edge: node id + position (4 lanes share each id -> bcast)
    int myid = bin[(size_t)cell * CAP + q];
    const float* np = npos + (size_t)myid * 3;
    float n0 = np[0], n1 = np[1], n2 = np[2];

    // ---- L1 direct in A-fragment layout: afrag[ks] = h1[q][ks*32+h*8 .. +8]
    bf16x8 afrag[4];
    #pragma unroll
    for (int ks = 0; ks < 4; ++ks) {
        int k0 = ks * 32 + h * 8;
        float4 wa0 = *(const float4*)(ew1 + 0 * HID + k0);
        float4 wa1 = *(const float4*)(ew1 + 0 * HID + k0 + 4);
        float4 wb0 = *(const float4*)(ew1 + 1 * HID + k0);
        float4 wb1 = *(const float4*)(ew1 + 1 * HID + k0 + 4);
        float4 wc0 = *(const float4*)(ew1 + 2 * HID + k0);
        float4 wc1 = *(const float4*)(ew1 + 2 * HID + k0 + 4);
        float4 pc0 = *(const float4*)(preC + (size_t)cell * HID + k0);
        float4 pc1 = *(const float4*)(preC + (size_t)cell * HID + k0 + 4);
        union { short s[8]; bf16x8 v; } o;
        o.s[0] = f2b(silu_f(pc0.x + n0 * wa0.x + n1 * wb0.x + n2 * wc0.x));
        o.s[1] = f2b(silu_f(pc0.y + n0 * wa0.y + n1 * wb0.y + n2 * wc0.y));
        o.s[2] = f2b(silu_f(pc0.z + n0 * wa0.z + n1 * wb0.z + n2 * wc0.z));
        o.s[3] = f2b(silu_f(pc0.w + n0 * wa0.w + n1 * wb0.w + n2 * wc0.w));
        o.s[4] = f2b(silu_f(pc1.x + n0 * wa1.x + n1 * wb1.x + n2 * wc1.x));
        o.s[5] = f2b(silu_f(pc1.y + n0 * wa1.y + n1 * wb1.y + n2 * wc1.y));
        o.s[6] = f2b(silu_f(pc1.z + n0 * wa1.z + n1 * wb1.z + n2 * wc1.z));
        o.s[7] = f2b(silu_f(pc1.w + n0 * wa1.w + n1 * wb1.w + n2 * wc1.w));
        afrag[ks] = o.v;
    }

    // ---- T14: pre[] gather for epi rows h*4+r, cols 16f+q (consumed post-GEMM)
    int ide[4];
    #pragma unroll
    for (int r = 0; r < 4; ++r)
        ide[r] = bin[(size_t)cell * CAP + h * 4 + r];
    unsigned short pg[4][8];
    #pragma unroll
    for (int r = 0; r < 4; ++r) {
        const unsigned short* pr = pre + (size_t)ide[r] * HID + q;
        #pragma unroll
        for (int f = 0; f < 8; ++f)
            pg[r][f] = pr[f * 16];
    }

    // ---- T-GEMM: C[16 edges][128 cols] = h1 @ T, acc[f] = cols 16f..16f+15
    f32x4 acc[8];
    #pragma unroll
    for (int f = 0; f < 8; ++f) acc[f] = (f32x4)(0.0f);
    const short* wT = wt + WT_T + q * 128 + h * 8;
    #pragma unroll
    for (int ks = 0; ks < 4; ++ks) {
        #pragma unroll
        for (int f = 0; f < 8; ++f) {
            bf16x8 b = *(const bf16x8*)(wT + f * (16 * 128) + ks * 32);
            acc[f] = MFMA(afrag[ks], b, acc[f]);
        }
    }

    // ---- epi: silu(h2in + pre), sum over the cell's 16 edges -> s_red
    #pragma unroll
    for (int f = 0; f < 8; ++f) {
        f32x4 v = acc[f];
        float s = silu_f(v[0] + b2f(pg[0][f]));
        s += silu_f(v[1] + b2f(pg[1][f]));
        s += silu_f(v[2] + b2f(pg[2][f]));
        s += silu_f(v[3] + b2f(pg[3][f]));
        s += __shfl_xor(s, 16);
        s += __shfl_xor(s, 32);
        if (h == 0)
            s_red[w * HID + f * 16 + q] = f2b(s);
    }
    __syncthreads();                     // only barrier

    // ---- coalesced store: 4 cells x 256B = 1KB contiguous
    {
        const unsigned* src = (const unsigned*)s_red;
        unsigned* dst = (unsigned*)(gsum + (size_t)c0 * HID);
        dst[t] = src[t];
    }
}

// ---------------------------------------------------------------------------
// update kernel: 64 cells/block, dense. gsum -> W2U GEMM -> silu(*inv+bU) ->
// U2 GEMM -> out. All 64 C-rows real.
// ---------------------------------------------------------------------------
extern "C" __global__ void __launch_bounds__(256, 4)
update_kernel(const float* __restrict__ ub2, const float* __restrict__ bU,
              const short* __restrict__ wt, const int* __restrict__ cnt,
              const unsigned short* __restrict__ gsum, float* __restrict__ out)
{
    __shared__ short s_x[64 * LDK];
    __shared__ short s_u[64 * LDK];
    __shared__ float s_inv[64];

    const int t  = threadIdx.x;
    const int c0 = blockIdx.x * 64;

    {   // stage 64 bf16 sum rows (raw copy) into padded LDS
        int row = t >> 2, part = t & 3;
        const uint4* src = (const uint4*)(gsum + (size_t)(c0 + row) * HID + part * 32);
        uint4* dst = (uint4*)(s_x + row * LDK + part * 32);
        dst[0] = src[0]; dst[1] = src[1]; dst[2] = src[2]; dst[3] = src[3];
    }
    if (t < 64) {
        int c = cnt[c0 + t];
        s_inv[t] = 1.0f / (float)(c > 0 ? c : 1);
    }
    __syncthreads();

    const int lane = t & 63, q = lane & 15, h = lane >> 4, nb = (t >> 6) * 32;
    f32x4 acc[4][2];
    #pragma unroll
    for (int m = 0; m < 4; ++m) { acc[m][0] = (f32x4)(0.0f); acc[m][1] = (f32x4)(0.0f); }
    gemm128<128>(acc, s_x + q * LDK + h * 8, wt + WT_W2U + (nb + q) * 128 + h * 8);

    // u1 = silu(acc*inv[row] + bU) -> s_u
    #pragma unroll
    for (int nf = 0; nf < 2; ++nf) {
        int n = nb + nf * 16 + q;
        float bb = bU[n];
        #pragma unroll
        for (int m = 0; m < 4; ++m) {
            #pragma unroll
            for (int r = 0; r < 4; ++r) {
                int row = m * 16 + h * 4 + r;
                s_u[row * LDK + n] = f2b(silu_f(acc[m][nf][r] * s_inv[row] + bb));
            }
        }
    }
    __syncthreads();

    #pragma unroll
    for (int m = 0; m < 4; ++m) { acc[m][0] = (f32x4)(0.0f); acc[m][1] = (f32x4)(0.0f); }
    gemm128<128>(acc, s_u + q * LDK + h * 8, wt + WT_U2 + (nb + q) * 128 + h * 8);

    #pragma unroll
    for (int nf = 0; nf < 2; ++nf) {
        int n = nb + nf * 16 + q;
        float bb = ub2[n];
        #pragma unroll
        for (int m = 0; m < 4; ++m)
            #pragma unroll
            for (int r = 0; r < 4; ++r)
                out[(size_t)(c0 + m * 16 + h * 4 + r) * HID + n] = acc[m][nf][r] + bb;
    }
}

// ---------------------------------------------------------------------------
extern "C" void kernel_launch(void* const* d_in, const int* in_sizes, int n_in,
                              void* d_out, int out_size, void* d_ws, size_t ws_size,
                              hipStream_t stream)
{
    const float* emb  = (const float*)d_in[0];
    const float* npos = (const float*)d_in[1];
    const float* gpos = (const float*)d_in[2];
    const int*   ei   = (const int*)d_in[3];
    const float* ew1  = (const float*)d_in[4];
    const float* eb1  = (const float*)d_in[5];
    const float* ew2  = (const float*)d_in[6];
    const float* eb2  = (const float*)d_in[7];
    const float* mw1  = (const float*)d_in[8];
    const float* mb1  = (const float*)d_in[9];
    const float* mw2  = (const float*)d_in[10];
    const float* mb2  = (const float*)d_in[11];
    const float* uw1  = (const float*)d_in[12];
    const float* ub1  = (const float*)d_in[13];
    const float* uw2  = (const float*)d_in[14];
    const float* ub2  = (const float*)d_in[15];

    const int E  = in_sizes[3] / 2;
    const int G  = in_sizes[2] / 3;
    const int NN = in_sizes[0] / HID;

    // ws: pre bf16[NN*128] | preC f32[G*128] | gsum bf16[G*128] | cnt int[G]
    //   | bin int[G*CAP] | wt bf16[WT_TOTAL] | bias2 f32[128] | bU f32[128]
    unsigned short* pre  = (unsigned short*)d_ws;
    float*          preC = (float*)(pre + (size_t)NN * HID);
    unsigned short* gsum = (unsigned short*)(preC + (size_t)G * HID);
    char* p = (char*)(gsum + (size_t)G * HID);
    int*   cnt = (int*)p;                 p += (size_t)G * 4;
    int*   bin = (int*)p;                 p += (size_t)G * CAP * 4;
    short* wt  = (short*)p;               p += (size_t)WT_TOTAL * 2;
    float* bias2 = (float*)p;             p += HID * 4;
    float* bU    = (float*)p;

    hipMemsetAsync(cnt, 0, (size_t)G * 4, stream);   // cnt only (bin fully written)

    int nbin  = (E + 255) / 256;
    int nprec = (G * 16 + 255) / 256;
    prep0<<<nbin + 128 + 64 + 64 + 1 + nprec, 256, 0, stream>>>(
        ei, cnt, bin, E, ew1, eb1, ew2, eb2, mw1, mw2, mb2, uw1, ub1, uw2,
        gpos, wt, bias2, bU, preC, G);
    prep_gemm<<<NN / 64, 256, 0, stream>>>(emb, mb1, bias2, wt, pre);
    edge_kernel<<<G / CPB, 256, 0, stream>>>(npos, ew1, wt, bin, pre, preC, gsum);
    update_kernel<<<G / 64, 256, 0, stream>>>(ub2, bU, wt, cnt, gsum, (float*)d_out);
}

// Round 15
// 132.367 us; speedup vs baseline: 1.8682x; 1.8682x over previous
//
#include <hip/hip_runtime.h>
#include <hip/hip_bf16.h>

#define HID 128
#define LDK 136    // LDS row stride in shorts (272B): +4-bank skew/row, additive offsets
#define CPB 4      // cells per edge-block
#define CAP 16     // edges per cell (E/G)

// wt regions (bf16 elements), all [128][128] transposed Wt[n][k]
#define WT_M1L 0       // mw1 rows 0..127 (prep_gemm)
#define WT_T   16384   // T fold: Tt[n][a] = sum_f ew2[a][f]*mw1[128+f][n]
#define WT_W2U 32768   // W2U fold: [n][a] = sum_f mw2[a][f]*uw1[f][n]
#define WT_U2  49152
#define WT_TOTAL 65536

typedef __attribute__((ext_vector_type(8))) short bf16x8;
typedef __attribute__((ext_vector_type(4))) float f32x4;

#define MFMA(a, b, c) __builtin_amdgcn_mfma_f32_16x16x32_bf16(a, b, c, 0, 0, 0)

// fast silu: raw v_rcp_f32 (~1 ulp) instead of IEEE divide sequence.
// Tolerance is 2% relative; bf16 storage rounds to 2^-8 anyway.
__device__ __forceinline__ float silu_f(float x) {
    float e = __expf(-x);
    return x * __builtin_amdgcn_rcpf(1.0f + e);
}

__device__ __forceinline__ short f2b(float x) {
    __hip_bfloat16 h = __float2bfloat16(x);   // RNE
    return *(short*)&h;
}

__device__ __forceinline__ float b2f(unsigned short u) {
    union { unsigned u32; float f; } v;
    v.u32 = ((unsigned)u) << 16;
    return v.f;
}

// K=128 GEMM, 4 act-row-tiles (rows e4*16+q) x 32 weight cols, act-as-A.
template<int LDB>
__device__ __forceinline__ void gemm128(f32x4 acc[4][2], const short* actb,
                                        const short* __restrict__ w0)
{
    const short* __restrict__ w1 = w0 + 16 * LDB;
    #pragma unroll
    for (int ks = 0; ks < 4; ++ks) {
        bf16x8 wa = *(const bf16x8*)(w0 + ks * 32);
        bf16x8 wb = *(const bf16x8*)(w1 + ks * 32);
        #pragma unroll
        for (int e4 = 0; e4 < 4; ++e4) {
            bf16x8 a = *(const bf16x8*)(actb + e4 * (16 * LDK) + ks * 32);
            acc[e4][0] = MFMA(a, wa, acc[e4][0]);
            acc[e4][1] = MFMA(a, wb, acc[e4][1]);
        }
    }
}

// ---------------------------------------------------------------------------
// prep0: binning | wt cvt (M1L,U2) | T fold | W2U fold | biases | preC
// ---------------------------------------------------------------------------
extern "C" __global__ void __launch_bounds__(256)
prep0(const int* __restrict__ ei, int* __restrict__ cnt, int* __restrict__ bin, int E,
      const float* __restrict__ ew1, const float* __restrict__ eb1,
      const float* __restrict__ ew2, const float* __restrict__ eb2,
      const float* __restrict__ mw1, const float* __restrict__ mw2,
      const float* __restrict__ mb2,
      const float* __restrict__ uw1, const float* __restrict__ ub1,
      const float* __restrict__ uw2,
      const float* __restrict__ gpos,
      short* __restrict__ wt, float* __restrict__ bias2, float* __restrict__ bU,
      float* __restrict__ preC, int G)
{
    int nbin = (E + 255) / 256;
    int b = blockIdx.x;
    int t = threadIdx.x;
    if (b < nbin) {                      // binning: store SOURCE NODE id
        int e = b * 256 + t;
        if (e < E) {
            int j = ei[E + e];
            int i = ei[e];
            int slot = atomicAdd(&cnt[j], 1);
            if (slot < CAP) bin[(size_t)j * CAP + slot] = i;
        }
        return;
    }
    b -= nbin;
    if (b < 128) {                       // transpose-convert M1L | U2
        int idx = b * 256 + t;
        if (idx < 16384) {
            int n = idx >> 7, k = idx & 127;
            wt[WT_M1L + idx] = f2b(mw1[k * HID + n]);
        } else {
            int r = idx - 16384;
            int n = r >> 7, k = r & 127;
            wt[WT_U2 + r] = f2b(uw2[k * HID + n]);
        }
        return;
    }
    b -= 128;
    if (b < 64) {                        // T fold
        int idx = b * 256 + t;
        int n = idx >> 7, a = idx & 127;
        const float* er = ew2 + (size_t)a * HID;
        float s = 0.0f;
        for (int f = 0; f < HID; ++f)
            s = fmaf(er[f], mw1[(size_t)(HID + f) * HID + n], s);
        wt[WT_T + idx] = f2b(s);
        return;
    }
    b -= 64;
    if (b < 64) {                        // W2U fold
        int idx = b * 256 + t;
        int n = idx >> 7, a = idx & 127;
        const float* mr = mw2 + (size_t)a * HID;
        float s = 0.0f;
        for (int f = 0; f < HID; ++f)
            s = fmaf(mr[f], uw1[(size_t)f * HID + n], s);
        wt[WT_W2U + idx] = f2b(s);
        return;
    }
    b -= 64;
    if (b < 1) {                         // bias2 (t<128) and bU (t>=128)
        if (t < HID) {
            float s = 0.0f;
            for (int f = 0; f < HID; ++f)
                s = fmaf(eb2[f], mw1[(size_t)(HID + f) * HID + t], s);
            bias2[t] = s;
        } else if (t < 2 * HID) {
            int n = t - HID;
            float s = 0.0f;
            for (int f = 0; f < HID; ++f)
                s = fmaf(mb2[f], uw1[(size_t)f * HID + n], s);
            bU[n] = s + ub1[n];
        }
        return;
    }
    b -= 1;
    {                                    // preC[cell][f] = gp.ew1[3:6] + eb1 (fp32)
        int idx = b * 256 + t;
        if (idx < G * 16) {
            int cell = idx >> 4, f0 = (idx & 15) * 8;
            const float* gp = gpos + (size_t)cell * 3;
            float g0 = gp[0], g1 = gp[1], g2 = gp[2];
            const float* w3 = ew1 + 3 * HID + f0;
            const float* w4 = ew1 + 4 * HID + f0;
            const float* w5 = ew1 + 5 * HID + f0;
            const float* bb = eb1 + f0;
            float o[8];
            #pragma unroll
            for (int j = 0; j < 8; ++j)
                o[j] = g0 * w3[j] + g1 * w4[j] + g2 * w5[j] + bb[j];
            float* dst = preC + (size_t)cell * HID + f0;
            *(float4*)dst       = make_float4(o[0], o[1], o[2], o[3]);
            *(float4*)(dst + 4) = make_float4(o[4], o[5], o[6], o[7]);
        }
    }
}

// ---------------------------------------------------------------------------
// prep_gemm: pre[node] = emb[node] @ mw1[:128] + mb1 + bias2   (bf16)
// ---------------------------------------------------------------------------
extern "C" __global__ void __launch_bounds__(256, 4)
prep_gemm(const float* __restrict__ emb, const float* __restrict__ mb1,
          const float* __restrict__ bias2, const short* __restrict__ wt,
          unsigned short* __restrict__ pre)
{
    __shared__ short s_x[64 * LDK];
    const int t  = threadIdx.x;
    const int r0 = blockIdx.x * 64;

    {   // stage 64 fp32 rows -> bf16 LDS (padded rows)
        int row = t >> 2, part = t & 3;
        const float4* src = (const float4*)(emb + (size_t)(r0 + row) * HID + part * 32);
        short* dst = s_x + row * LDK + part * 32;
        #pragma unroll
        for (int c = 0; c < 4; ++c) {
            float4 v0 = src[c * 2], v1 = src[c * 2 + 1];
            short4 a4, b4;
            a4.x = f2b(v0.x); a4.y = f2b(v0.y); a4.z = f2b(v0.z); a4.w = f2b(v0.w);
            b4.x = f2b(v1.x); b4.y = f2b(v1.y); b4.z = f2b(v1.z); b4.w = f2b(v1.w);
            *(short4*)(dst + c * 8)     = a4;
            *(short4*)(dst + c * 8 + 4) = b4;
        }
    }
    __syncthreads();

    const int lane = t & 63, q = lane & 15, h = lane >> 4, nb = (t >> 6) * 32;
    f32x4 acc[4][2];
    #pragma unroll
    for (int m = 0; m < 4; ++m) { acc[m][0] = (f32x4)(0.0f); acc[m][1] = (f32x4)(0.0f); }
    gemm128<128>(acc, s_x + q * LDK + h * 8, wt + WT_M1L + (nb + q) * 128 + h * 8);

    #pragma unroll
    for (int nf = 0; nf < 2; ++nf) {
        int n = nb + nf * 16 + q;
        float bb = mb1[n] + bias2[n];
        #pragma unroll
        for (int m = 0; m < 4; ++m)
            #pragma unroll
            for (int r = 0; r < 4; ++r)
                pre[(size_t)(r0 + m * 16 + h * 4 + r) * HID + n] =
                    f2b(acc[m][nf][r] + bb);
    }
}

// ---------------------------------------------------------------------------
// edge kernel: 4 cells x 16 edges. L1 (np FMAs + preC) -> B1 -> T-GEMM ->
// silu+pre in regs -> per-cell sum -> s_red -> B2 -> coalesced 1KB store.
// ---------------------------------------------------------------------------
extern "C" __global__ void __launch_bounds__(256, 6)
edge_kernel(const float* __restrict__ npos,
            const float* __restrict__ ew1,
            const short* __restrict__ wt,
            const int* __restrict__ bin,
            const unsigned short* __restrict__ pre,
            const float* __restrict__ preC,
            unsigned short* __restrict__ gsum)
{
    __shared__ short s_h1[64 * LDK];   // h1 acts
    __shared__ short s_red[4 * HID];   // per-cell sums (bf16), bounce buffer
    __shared__ int   s_bin[64];        // node ids, staged once

    const int t  = threadIdx.x;
    const int c0 = blockIdx.x * CPB;
    const int lane = t & 63, q = lane & 15, h = lane >> 4, nb = (t >> 6) * 32;

    if (t < 64) s_bin[t] = bin[c0 * CAP + t];

    // ---- ids for L1 rows (e4*16+q); edge row e4*16+q belongs to cell c0+e4
    int idL[4];
    #pragma unroll
    for (int e4 = 0; e4 < 4; ++e4)
        idL[e4] = bin[c0 * CAP + e4 * 16 + q];

    float np0[4], np1[4], np2[4];
    #pragma unroll
    for (int e4 = 0; e4 < 4; ++e4) {
        const float* p = npos + (size_t)idL[e4] * 3;
        np0[e4] = p[0]; np1[e4] = p[1]; np2[e4] = p[2];
    }

    const int f00 = nb + h * 4;
    short* wx = s_h1 + q * LDK + nb + h * 4;   // L1 write base

    // ---- L1: h1 = silu(np . ew1[0:3] + preC[cell]) -> s_h1
    #pragma unroll
    for (int nf = 0; nf < 2; ++nf) {
        int f0 = f00 + nf * 16;
        float4 wn0 = *(const float4*)(ew1 + 0 * HID + f0);
        float4 wn1 = *(const float4*)(ew1 + 1 * HID + f0);
        float4 wn2 = *(const float4*)(ew1 + 2 * HID + f0);
        #pragma unroll
        for (int e4 = 0; e4 < 4; ++e4) {
            float4 pc = *(const float4*)(preC + (size_t)(c0 + e4) * HID + f0);
            float z0 = silu_f(pc.x + np0[e4] * wn0.x + np1[e4] * wn1.x + np2[e4] * wn2.x);
            float z1 = silu_f(pc.y + np0[e4] * wn0.y + np1[e4] * wn1.y + np2[e4] * wn2.y);
            float z2 = silu_f(pc.z + np0[e4] * wn0.z + np1[e4] * wn1.z + np2[e4] * wn2.z);
            float z3 = silu_f(pc.w + np0[e4] * wn0.w + np1[e4] * wn1.w + np2[e4] * wn2.w);
            short4 s4;
            s4.x = f2b(z0); s4.y = f2b(z1); s4.z = f2b(z2); s4.w = f2b(z3);
            *(short4*)(wx + e4 * (16 * LDK) + nf * 16) = s4;
        }
    }
    __syncthreads();                                   // B1: h1 + s_bin visible

    // ---- pre[] gather from s_bin ids; loads issue here, consumed post-GEMM
    unsigned short pA[4][4], pB[4][4];
    #pragma unroll
    for (int m = 0; m < 4; ++m) {
        #pragma unroll
        for (int r = 0; r < 4; ++r) {
            int id = s_bin[m * 16 + h * 4 + r];
            const unsigned short* pr = pre + (size_t)id * HID;
            pA[m][r] = pr[nb + q];
            pB[m][r] = pr[nb + 16 + q];
        }
    }

    // ---- T-GEMM: h2in = h1 @ T  (actA: C rows = edges, cols nb(+16)+q)
    f32x4 acc[4][2];
    #pragma unroll
    for (int m = 0; m < 4; ++m) { acc[m][0] = (f32x4)(0.0f); acc[m][1] = (f32x4)(0.0f); }
    gemm128<128>(acc, s_h1 + q * LDK + h * 8, wt + WT_T + (nb + q) * 128 + h * 8);

    // ---- silu(h2in + pre) in regs; per-cell sum -> s_red (1/c deferred)
    #pragma unroll
    for (int m = 0; m < 4; ++m) {
        #pragma unroll
        for (int nf = 0; nf < 2; ++nf) {
            f32x4 v = acc[m][nf];
            float s = silu_f(v[0] + b2f(nf ? pB[m][0] : pA[m][0]));
            s += silu_f(v[1] + b2f(nf ? pB[m][1] : pA[m][1]));
            s += silu_f(v[2] + b2f(nf ? pB[m][2] : pA[m][2]));
            s += silu_f(v[3] + b2f(nf ? pB[m][3] : pA[m][3]));
            s += __shfl_xor(s, 16);
            s += __shfl_xor(s, 32);
            if (h == 0)
                s_red[m * HID + nb + nf * 16 + q] = f2b(s);
        }
    }
    __syncthreads();                                   // B2: s_red complete

    // ---- coalesced store: 4 rows x 256B = 1KB contiguous (cells c0..c0+3)
    {
        const unsigned* src = (const unsigned*)s_red;
        unsigned* dst = (unsigned*)(gsum + (size_t)c0 * HID);
        dst[t] = src[t];
    }
}

// ---------------------------------------------------------------------------
// update kernel: 64 cells/block, dense. gsum -> W2U GEMM -> silu(*inv+bU) ->
// U2 GEMM -> out. All 64 C-rows real.
// ---------------------------------------------------------------------------
extern "C" __global__ void __launch_bounds__(256, 4)
update_kernel(const float* __restrict__ ub2, const float* __restrict__ bU,
              const short* __restrict__ wt, const int* __restrict__ cnt,
              const unsigned short* __restrict__ gsum, float* __restrict__ out)
{
    __shared__ short s_x[64 * LDK];
    __shared__ short s_u[64 * LDK];
    __shared__ float s_inv[64];

    const int t  = threadIdx.x;
    const int c0 = blockIdx.x * 64;

    {   // stage 64 bf16 sum rows (raw copy) into padded LDS
        int row = t >> 2, part = t & 3;
        const uint4* src = (const uint4*)(gsum + (size_t)(c0 + row) * HID + part * 32);
        uint4* dst = (uint4*)(s_x + row * LDK + part * 32);
        dst[0] = src[0]; dst[1] = src[1]; dst[2] = src[2]; dst[3] = src[3];
    }
    if (t < 64) {
        int c = cnt[c0 + t];
        s_inv[t] = 1.0f / (float)(c > 0 ? c : 1);
    }
    __syncthreads();

    const int lane = t & 63, q = lane & 15, h = lane >> 4, nb = (t >> 6) * 32;
    f32x4 acc[4][2];
    #pragma unroll
    for (int m = 0; m < 4; ++m) { acc[m][0] = (f32x4)(0.0f); acc[m][1] = (f32x4)(0.0f); }
    gemm128<128>(acc, s_x + q * LDK + h * 8, wt + WT_W2U + (nb + q) * 128 + h * 8);

    // u1 = silu(acc*inv[row] + bU) -> s_u
    #pragma unroll
    for (int nf = 0; nf < 2; ++nf) {
        int n = nb + nf * 16 + q;
        float bb = bU[n];
        #pragma unroll
        for (int m = 0; m < 4; ++m) {
            #pragma unroll
            for (int r = 0; r < 4; ++r) {
                int row = m * 16 + h * 4 + r;
                s_u[row * LDK + n] = f2b(silu_f(acc[m][nf][r] * s_inv[row] + bb));
            }
        }
    }
    __syncthreads();

    #pragma unroll
    for (int m = 0; m < 4; ++m) { acc[m][0] = (f32x4)(0.0f); acc[m][1] = (f32x4)(0.0f); }
    gemm128<128>(acc, s_u + q * LDK + h * 8, wt + WT_U2 + (nb + q) * 128 + h * 8);

    #pragma unroll
    for (int nf = 0; nf < 2; ++nf) {
        int n = nb + nf * 16 + q;
        float bb = ub2[n];
        #pragma unroll
        for (int m = 0; m < 4; ++m)
            #pragma unroll
            for (int r = 0; r < 4; ++r)
                out[(size_t)(c0 + m * 16 + h * 4 + r) * HID + n] = acc[m][nf][r] + bb;
    }
}

// ---------------------------------------------------------------------------
extern "C" void kernel_launch(void* const* d_in, const int* in_sizes, int n_in,
                              void* d_out, int out_size, void* d_ws, size_t ws_size,
                              hipStream_t stream)
{
    const float* emb  = (const float*)d_in[0];
    const float* npos = (const float*)d_in[1];
    const float* gpos = (const float*)d_in[2];
    const int*   ei   = (const int*)d_in[3];
    const float* ew1  = (const float*)d_in[4];
    const float* eb1  = (const float*)d_in[5];
    const float* ew2  = (const float*)d_in[6];
    const float* eb2  = (const float*)d_in[7];
    const float* mw1  = (const float*)d_in[8];
    const float* mb1  = (const float*)d_in[9];
    const float* mw2  = (const float*)d_in[10];
    const float* mb2  = (const float*)d_in[11];
    const float* uw1  = (const float*)d_in[12];
    const float* ub1  = (const float*)d_in[13];
    const float* uw2  = (const float*)d_in[14];
    const float* ub2  = (const float*)d_in[15];

    const int E  = in_sizes[3] / 2;
    const int G  = in_sizes[2] / 3;
    const int NN = in_sizes[0] / HID;

    // ws: pre bf16[NN*128] | preC f32[G*128] | gsum bf16[G*128] | cnt int[G]
    //   | bin int[G*CAP] | wt bf16[WT_TOTAL] | bias2 f32[128] | bU f32[128]
    unsigned short* pre  = (unsigned short*)d_ws;
    float*          preC = (float*)(pre + (size_t)NN * HID);
    unsigned short* gsum = (unsigned short*)(preC + (size_t)G * HID);
    char* p = (char*)(gsum + (size_t)G * HID);
    int*   cnt = (int*)p;                 p += (size_t)G * 4;
    int*   bin = (int*)p;                 p += (size_t)G * CAP * 4;
    short* wt  = (short*)p;               p += (size_t)WT_TOTAL * 2;
    float* bias2 = (float*)p;             p += HID * 4;
    float* bU    = (float*)p;

    hipMemsetAsync(cnt, 0, (size_t)G * 4, stream);   // cnt only (bin fully written)

    int nbin  = (E + 255) / 256;
    int nprec = (G * 16 + 255) / 256;
    prep0<<<nbin + 128 + 64 + 64 + 1 + nprec, 256, 0, stream>>>(
        ei, cnt, bin, E, ew1, eb1, ew2, eb2, mw1, mw2, mb2, uw1, ub1, uw2,
        gpos, wt, bias2, bU, preC, G);
    prep_gemm<<<NN / 64, 256, 0, stream>>>(emb, mb1, bias2, wt, pre);
    edge_kernel<<<G / CPB, 256, 0, stream>>>(npos, ew1, wt, bin, pre, preC, gsum);
    update_kernel<<<G / 64, 256, 0, stream>>>(ub2, bU, wt, cnt, gsum, (float*)d_out);
}

// Round 16
// 127.751 us; speedup vs baseline: 1.9357x; 1.0361x over previous
//
#include <hip/hip_runtime.h>
#include <hip/hip_bf16.h>

#define HID 128
#define LDK 136    // LDS row stride in shorts (272B): +4-bank skew/row, additive offsets
#define CPB 4      // cells per edge-block
#define CAP 16     // edges per cell (E/G)

// wt regions (bf16 elements), all [128][128] transposed Wt[n][k]
#define WT_M1L 0       // mw1 rows 0..127 (prep_gemm)
#define WT_T   16384   // T fold: Tt[n][a] = sum_f ew2[a][f]*mw1[128+f][n]
#define WT_W2U 32768   // W2U fold: [n][a] = sum_f mw2[a][f]*uw1[f][n]
#define WT_U2  49152
#define WT_TOTAL 65536

typedef __attribute__((ext_vector_type(8))) short bf16x8;
typedef __attribute__((ext_vector_type(4))) float f32x4;

#define MFMA(a, b, c) __builtin_amdgcn_mfma_f32_16x16x32_bf16(a, b, c, 0, 0, 0)

// fast silu: raw v_rcp_f32 (~1 ulp) instead of IEEE divide sequence.
__device__ __forceinline__ float silu_f(float x) {
    float e = __expf(-x);
    return x * __builtin_amdgcn_rcpf(1.0f + e);
}

__device__ __forceinline__ short f2b(float x) {
    __hip_bfloat16 h = __float2bfloat16(x);   // RNE
    return *(short*)&h;
}

__device__ __forceinline__ float b2f(unsigned short u) {
    union { unsigned u32; float f; } v;
    v.u32 = ((unsigned)u) << 16;
    return v.f;
}

// K=128 GEMM, 4 act-row-tiles (rows e4*16+q) x 32 weight cols, act-as-A.
template<int LDB>
__device__ __forceinline__ void gemm128(f32x4 acc[4][2], const short* actb,
                                        const short* __restrict__ w0)
{
    const short* __restrict__ w1 = w0 + 16 * LDB;
    #pragma unroll
    for (int ks = 0; ks < 4; ++ks) {
        bf16x8 wa = *(const bf16x8*)(w0 + ks * 32);
        bf16x8 wb = *(const bf16x8*)(w1 + ks * 32);
        #pragma unroll
        for (int e4 = 0; e4 < 4; ++e4) {
            bf16x8 a = *(const bf16x8*)(actb + e4 * (16 * LDK) + ks * 32);
            acc[e4][0] = MFMA(a, wa, acc[e4][0]);
            acc[e4][1] = MFMA(a, wb, acc[e4][1]);
        }
    }
}

// ---------------------------------------------------------------------------
// prep0: binning | wt cvt (M1L,U2) | T fold | W2U fold | biases | preC
// ---------------------------------------------------------------------------
extern "C" __global__ void __launch_bounds__(256)
prep0(const int* __restrict__ ei, int* __restrict__ cnt, int* __restrict__ bin, int E,
      const float* __restrict__ ew1, const float* __restrict__ eb1,
      const float* __restrict__ ew2, const float* __restrict__ eb2,
      const float* __restrict__ mw1, const float* __restrict__ mw2,
      const float* __restrict__ mb2,
      const float* __restrict__ uw1, const float* __restrict__ ub1,
      const float* __restrict__ uw2,
      const float* __restrict__ gpos,
      short* __restrict__ wt, float* __restrict__ bias2, float* __restrict__ bU,
      float* __restrict__ preC, int G)
{
    int nbin = (E + 255) / 256;
    int b = blockIdx.x;
    int t = threadIdx.x;
    if (b < nbin) {                      // binning: store SOURCE NODE id
        int e = b * 256 + t;
        if (e < E) {
            int j = ei[E + e];
            int i = ei[e];
            int slot = atomicAdd(&cnt[j], 1);
            if (slot < CAP) bin[(size_t)j * CAP + slot] = i;
        }
        return;
    }
    b -= nbin;
    if (b < 128) {                       // transpose-convert M1L | U2
        int idx = b * 256 + t;
        if (idx < 16384) {
            int n = idx >> 7, k = idx & 127;
            wt[WT_M1L + idx] = f2b(mw1[k * HID + n]);
        } else {
            int r = idx - 16384;
            int n = r >> 7, k = r & 127;
            wt[WT_U2 + r] = f2b(uw2[k * HID + n]);
        }
        return;
    }
    b -= 128;
    if (b < 64) {                        // T fold (a wave-uniform, n lane-consec)
        int idx = b * 256 + t;
        int a = idx >> 7, n = idx & 127;
        const float* er = ew2 + (size_t)a * HID;        // broadcast (scalar) loads
        float s = 0.0f;
        for (int f = 0; f < HID; ++f)
            s = fmaf(er[f], mw1[(size_t)(HID + f) * HID + n], s);  // coalesced
        wt[WT_T + n * HID + a] = f2b(s);
        return;
    }
    b -= 64;
    if (b < 64) {                        // W2U fold (same coalesced pattern)
        int idx = b * 256 + t;
        int a = idx >> 7, n = idx & 127;
        const float* mr = mw2 + (size_t)a * HID;        // broadcast
        float s = 0.0f;
        for (int f = 0; f < HID; ++f)
            s = fmaf(mr[f], uw1[(size_t)f * HID + n], s);          // coalesced
        wt[WT_W2U + n * HID + a] = f2b(s);
        return;
    }
    b -= 64;
    if (b < 1) {                         // bias2 (t<128) and bU (t>=128)
        if (t < HID) {
            float s = 0.0f;
            for (int f = 0; f < HID; ++f)
                s = fmaf(eb2[f], mw1[(size_t)(HID + f) * HID + t], s);
            bias2[t] = s;
        } else if (t < 2 * HID) {
            int n = t - HID;
            float s = 0.0f;
            for (int f = 0; f < HID; ++f)
                s = fmaf(mb2[f], uw1[(size_t)f * HID + n], s);
            bU[n] = s + ub1[n];
        }
        return;
    }
    b -= 1;
    {                                    // preC[cell][f] = gp.ew1[3:6] + eb1 (fp32)
        int idx = b * 256 + t;
        if (idx < G * 16) {
            int cell = idx >> 4, f0 = (idx & 15) * 8;
            const float* gp = gpos + (size_t)cell * 3;
            float g0 = gp[0], g1 = gp[1], g2 = gp[2];
            const float* w3 = ew1 + 3 * HID + f0;
            const float* w4 = ew1 + 4 * HID + f0;
            const float* w5 = ew1 + 5 * HID + f0;
            const float* bb = eb1 + f0;
            float o[8];
            #pragma unroll
            for (int j = 0; j < 8; ++j)
                o[j] = g0 * w3[j] + g1 * w4[j] + g2 * w5[j] + bb[j];
            float* dst = preC + (size_t)cell * HID + f0;
            *(float4*)dst       = make_float4(o[0], o[1], o[2], o[3]);
            *(float4*)(dst + 4) = make_float4(o[4], o[5], o[6], o[7]);
        }
    }
}

// ---------------------------------------------------------------------------
// prep_gemm: pre[node] = emb[node] @ mw1[:128] + mb1 + bias2   (bf16)
// Epilogue via LDS bounce -> fully coalesced 16KB store (no 2B scatter RFO).
// ---------------------------------------------------------------------------
extern "C" __global__ void __launch_bounds__(256, 4)
prep_gemm(const float* __restrict__ emb, const float* __restrict__ mb1,
          const float* __restrict__ bias2, const short* __restrict__ wt,
          unsigned short* __restrict__ pre)
{
    __shared__ short s_x[64 * LDK];
    const int t  = threadIdx.x;
    const int r0 = blockIdx.x * 64;

    {   // stage 64 fp32 rows -> bf16 LDS (padded rows)
        int row = t >> 2, part = t & 3;
        const float4* src = (const float4*)(emb + (size_t)(r0 + row) * HID + part * 32);
        short* dst = s_x + row * LDK + part * 32;
        #pragma unroll
        for (int c = 0; c < 4; ++c) {
            float4 v0 = src[c * 2], v1 = src[c * 2 + 1];
            short4 a4, b4;
            a4.x = f2b(v0.x); a4.y = f2b(v0.y); a4.z = f2b(v0.z); a4.w = f2b(v0.w);
            b4.x = f2b(v1.x); b4.y = f2b(v1.y); b4.z = f2b(v1.z); b4.w = f2b(v1.w);
            *(short4*)(dst + c * 8)     = a4;
            *(short4*)(dst + c * 8 + 4) = b4;
        }
    }
    __syncthreads();

    const int lane = t & 63, q = lane & 15, h = lane >> 4, nb = (t >> 6) * 32;
    f32x4 acc[4][2];
    #pragma unroll
    for (int m = 0; m < 4; ++m) { acc[m][0] = (f32x4)(0.0f); acc[m][1] = (f32x4)(0.0f); }
    gemm128<128>(acc, s_x + q * LDK + h * 8, wt + WT_M1L + (nb + q) * 128 + h * 8);

    __syncthreads();                     // all gemm reads of s_x done; reuse as bounce
    #pragma unroll
    for (int nf = 0; nf < 2; ++nf) {
        int n = nb + nf * 16 + q;
        float bb = mb1[n] + bias2[n];
        #pragma unroll
        for (int m = 0; m < 4; ++m)
            #pragma unroll
            for (int r = 0; r < 4; ++r)
                s_x[(m * 16 + h * 4 + r) * LDK + n] = f2b(acc[m][nf][r] + bb);
    }
    __syncthreads();
    {   // coalesced copy-out: 64 rows x 256B = 16KB contiguous
        uint4* dst = (uint4*)(pre + (size_t)r0 * HID);
        #pragma unroll
        for (int i = 0; i < 4; ++i) {
            int chunk = i * 256 + t;         // 0..1023
            int row = chunk >> 4, off = chunk & 15;
            dst[chunk] = *(const uint4*)(s_x + row * LDK + off * 8);
        }
    }
}

// ---------------------------------------------------------------------------
// edge kernel: 4 cells x 16 edges. L1 (np FMAs + preC) -> B1 -> T-GEMM ->
// silu+pre in regs -> per-cell sum -> s_red -> B2 -> coalesced 1KB store.
// (UNCHANGED from round 15)
// ---------------------------------------------------------------------------
extern "C" __global__ void __launch_bounds__(256, 6)
edge_kernel(const float* __restrict__ npos,
            const float* __restrict__ ew1,
            const short* __restrict__ wt,
            const int* __restrict__ bin,
            const unsigned short* __restrict__ pre,
            const float* __restrict__ preC,
            unsigned short* __restrict__ gsum)
{
    __shared__ short s_h1[64 * LDK];   // h1 acts
    __shared__ short s_red[4 * HID];   // per-cell sums (bf16), bounce buffer
    __shared__ int   s_bin[64];        // node ids, staged once

    const int t  = threadIdx.x;
    const int c0 = blockIdx.x * CPB;
    const int lane = t & 63, q = lane & 15, h = lane >> 4, nb = (t >> 6) * 32;

    if (t < 64) s_bin[t] = bin[c0 * CAP + t];

    // ---- ids for L1 rows (e4*16+q); edge row e4*16+q belongs to cell c0+e4
    int idL[4];
    #pragma unroll
    for (int e4 = 0; e4 < 4; ++e4)
        idL[e4] = bin[c0 * CAP + e4 * 16 + q];

    float np0[4], np1[4], np2[4];
    #pragma unroll
    for (int e4 = 0; e4 < 4; ++e4) {
        const float* p = npos + (size_t)idL[e4] * 3;
        np0[e4] = p[0]; np1[e4] = p[1]; np2[e4] = p[2];
    }

    const int f00 = nb + h * 4;
    short* wx = s_h1 + q * LDK + nb + h * 4;   // L1 write base

    // ---- L1: h1 = silu(np . ew1[0:3] + preC[cell]) -> s_h1
    #pragma unroll
    for (int nf = 0; nf < 2; ++nf) {
        int f0 = f00 + nf * 16;
        float4 wn0 = *(const float4*)(ew1 + 0 * HID + f0);
        float4 wn1 = *(const float4*)(ew1 + 1 * HID + f0);
        float4 wn2 = *(const float4*)(ew1 + 2 * HID + f0);
        #pragma unroll
        for (int e4 = 0; e4 < 4; ++e4) {
            float4 pc = *(const float4*)(preC + (size_t)(c0 + e4) * HID + f0);
            float z0 = silu_f(pc.x + np0[e4] * wn0.x + np1[e4] * wn1.x + np2[e4] * wn2.x);
            float z1 = silu_f(pc.y + np0[e4] * wn0.y + np1[e4] * wn1.y + np2[e4] * wn2.y);
            float z2 = silu_f(pc.z + np0[e4] * wn0.z + np1[e4] * wn1.z + np2[e4] * wn2.z);
            float z3 = silu_f(pc.w + np0[e4] * wn0.w + np1[e4] * wn1.w + np2[e4] * wn2.w);
            short4 s4;
            s4.x = f2b(z0); s4.y = f2b(z1); s4.z = f2b(z2); s4.w = f2b(z3);
            *(short4*)(wx + e4 * (16 * LDK) + nf * 16) = s4;
        }
    }
    __syncthreads();                                   // B1: h1 + s_bin visible

    // ---- pre[] gather from s_bin ids; loads issue here, consumed post-GEMM
    unsigned short pA[4][4], pB[4][4];
    #pragma unroll
    for (int m = 0; m < 4; ++m) {
        #pragma unroll
        for (int r = 0; r < 4; ++r) {
            int id = s_bin[m * 16 + h * 4 + r];
            const unsigned short* pr = pre + (size_t)id * HID;
            pA[m][r] = pr[nb + q];
            pB[m][r] = pr[nb + 16 + q];
        }
    }

    // ---- T-GEMM: h2in = h1 @ T  (actA: C rows = edges, cols nb(+16)+q)
    f32x4 acc[4][2];
    #pragma unroll
    for (int m = 0; m < 4; ++m) { acc[m][0] = (f32x4)(0.0f); acc[m][1] = (f32x4)(0.0f); }
    gemm128<128>(acc, s_h1 + q * LDK + h * 8, wt + WT_T + (nb + q) * 128 + h * 8);

    // ---- silu(h2in + pre) in regs; per-cell sum -> s_red (1/c deferred)
    #pragma unroll
    for (int m = 0; m < 4; ++m) {
        #pragma unroll
        for (int nf = 0; nf < 2; ++nf) {
            f32x4 v = acc[m][nf];
            float s = silu_f(v[0] + b2f(nf ? pB[m][0] : pA[m][0]));
            s += silu_f(v[1] + b2f(nf ? pB[m][1] : pA[m][1]));
            s += silu_f(v[2] + b2f(nf ? pB[m][2] : pA[m][2]));
            s += silu_f(v[3] + b2f(nf ? pB[m][3] : pA[m][3]));
            s += __shfl_xor(s, 16);
            s += __shfl_xor(s, 32);
            if (h == 0)
                s_red[m * HID + nb + nf * 16 + q] = f2b(s);
        }
    }
    __syncthreads();                                   // B2: s_red complete

    // ---- coalesced store: 4 rows x 256B = 1KB contiguous (cells c0..c0+3)
    {
        const unsigned* src = (const unsigned*)s_red;
        unsigned* dst = (unsigned*)(gsum + (size_t)c0 * HID);
        dst[t] = src[t];
    }
}

// ---------------------------------------------------------------------------
// update kernel: 64 cells/block, dense. gsum -> W2U GEMM -> silu(*inv+bU) ->
// U2 GEMM -> out. All 64 C-rows real. (UNCHANGED)
// ---------------------------------------------------------------------------
extern "C" __global__ void __launch_bounds__(256, 4)
update_kernel(const float* __restrict__ ub2, const float* __restrict__ bU,
              const short* __restrict__ wt, const int* __restrict__ cnt,
              const unsigned short* __restrict__ gsum, float* __restrict__ out)
{
    __shared__ short s_x[64 * LDK];
    __shared__ short s_u[64 * LDK];
    __shared__ float s_inv[64];

    const int t  = threadIdx.x;
    const int c0 = blockIdx.x * 64;

    {   // stage 64 bf16 sum rows (raw copy) into padded LDS
        int row = t >> 2, part = t & 3;
        const uint4* src = (const uint4*)(gsum + (size_t)(c0 + row) * HID + part * 32);
        uint4* dst = (uint4*)(s_x + row * LDK + part * 32);
        dst[0] = src[0]; dst[1] = src[1]; dst[2] = src[2]; dst[3] = src[3];
    }
    if (t < 64) {
        int c = cnt[c0 + t];
        s_inv[t] = 1.0f / (float)(c > 0 ? c : 1);
    }
    __syncthreads();

    const int lane = t & 63, q = lane & 15, h = lane >> 4, nb = (t >> 6) * 32;
    f32x4 acc[4][2];
    #pragma unroll
    for (int m = 0; m < 4; ++m) { acc[m][0] = (f32x4)(0.0f); acc[m][1] = (f32x4)(0.0f); }
    gemm128<128>(acc, s_x + q * LDK + h * 8, wt + WT_W2U + (nb + q) * 128 + h * 8);

    // u1 = silu(acc*inv[row] + bU) -> s_u
    #pragma unroll
    for (int nf = 0; nf < 2; ++nf) {
        int n = nb + nf * 16 + q;
        float bb = bU[n];
        #pragma unroll
        for (int m = 0; m < 4; ++m) {
            #pragma unroll
            for (int r = 0; r < 4; ++r) {
                int row = m * 16 + h * 4 + r;
                s_u[row * LDK + n] = f2b(silu_f(acc[m][nf][r] * s_inv[row] + bb));
            }
        }
    }
    __syncthreads();

    #pragma unroll
    for (int m = 0; m < 4; ++m) { acc[m][0] = (f32x4)(0.0f); acc[m][1] = (f32x4)(0.0f); }
    gemm128<128>(acc, s_u + q * LDK + h * 8, wt + WT_U2 + (nb + q) * 128 + h * 8);

    #pragma unroll
    for (int nf = 0; nf < 2; ++nf) {
        int n = nb + nf * 16 + q;
        float bb = ub2[n];
        #pragma unroll
        for (int m = 0; m < 4; ++m)
            #pragma unroll
            for (int r = 0; r < 4; ++r)
                out[(size_t)(c0 + m * 16 + h * 4 + r) * HID + n] = acc[m][nf][r] + bb;
    }
}

// ---------------------------------------------------------------------------
extern "C" void kernel_launch(void* const* d_in, const int* in_sizes, int n_in,
                              void* d_out, int out_size, void* d_ws, size_t ws_size,
                              hipStream_t stream)
{
    const float* emb  = (const float*)d_in[0];
    const float* npos = (const float*)d_in[1];
    const float* gpos = (const float*)d_in[2];
    const int*   ei   = (const int*)d_in[3];
    const float* ew1  = (const float*)d_in[4];
    const float* eb1  = (const float*)d_in[5];
    const float* ew2  = (const float*)d_in[6];
    const float* eb2  = (const float*)d_in[7];
    const float* mw1  = (const float*)d_in[8];
    const float* mb1  = (const float*)d_in[9];
    const float* mw2  = (const float*)d_in[10];
    const float* mb2  = (const float*)d_in[11];
    const float* uw1  = (const float*)d_in[12];
    const float* ub1  = (const float*)d_in[13];
    const float* uw2  = (const float*)d_in[14];
    const float* ub2  = (const float*)d_in[15];

    const int E  = in_sizes[3] / 2;
    const int G  = in_sizes[2] / 3;
    const int NN = in_sizes[0] / HID;

    // ws: pre bf16[NN*128] | preC f32[G*128] | gsum bf16[G*128] | cnt int[G]
    //   | bin int[G*CAP] | wt bf16[WT_TOTAL] | bias2 f32[128] | bU f32[128]
    unsigned short* pre  = (unsigned short*)d_ws;
    float*          preC = (float*)(pre + (size_t)NN * HID);
    unsigned short* gsum = (unsigned short*)(preC + (size_t)G * HID);
    char* p = (char*)(gsum + (size_t)G * HID);
    int*   cnt = (int*)p;                 p += (size_t)G * 4;
    int*   bin = (int*)p;                 p += (size_t)G * CAP * 4;
    short* wt  = (short*)p;               p += (size_t)WT_TOTAL * 2;
    float* bias2 = (float*)p;             p += HID * 4;
    float* bU    = (float*)p;

    hipMemsetAsync(cnt, 0, (size_t)G * 4, stream);   // cnt only (bin fully written)

    int nbin  = (E + 255) / 256;
    int nprec = (G * 16 + 255) / 256;
    prep0<<<nbin + 128 + 64 + 64 + 1 + nprec, 256, 0, stream>>>(
        ei, cnt, bin, E, ew1, eb1, ew2, eb2, mw1, mw2, mb2, uw1, ub1, uw2,
        gpos, wt, bias2, bU, preC, G);
    prep_gemm<<<NN / 64, 256, 0, stream>>>(emb, mb1, bias2, wt, pre);
    edge_kernel<<<G / CPB, 256, 0, stream>>>(npos, ew1, wt, bin, pre, preC, gsum);
    update_kernel<<<G / 64, 256, 0, stream>>>(ub2, bU, wt, cnt, gsum, (float*)d_out);
}